// Round 3
// baseline (147.158 us; speedup 1.0000x reference)
//
#include <hip/hip_runtime.h>
#include <hip/hip_bf16.h>

#define NDOM 8
#define TN 32    // tile rows == cols
#define BK 128   // bf16 k-elems per LDS stage; row = 256 B = 16 chunks of 16 B

typedef short short8 __attribute__((ext_vector_type(8)));
typedef float f32x4 __attribute__((ext_vector_type(4)));

__device__ inline unsigned short f2bf(float f) {
    unsigned u = __float_as_uint(f);
    u = (u + 0x7FFFu + ((u >> 16) & 1u)) >> 16;  // RNE
    return (unsigned short)u;
}

__device__ inline void gload16(const void* g, void* l) {
    __builtin_amdgcn_global_load_lds(
        (const __attribute__((address_space(1))) unsigned int*)g,
        (__attribute__((address_space(3))) unsigned int*)l, 16, 0, 0);
}

// ---------------------------------------------------------------- bucket ----
// Single block, 4 waves. Labels staged to LDS once (independent int4 loads),
// then ballot/popc counting + rank scatter entirely from LDS.
__global__ void k_bucket(const int* __restrict__ labels, int B,
                         int* __restrict__ perm, int* __restrict__ dom_off,
                         int* __restrict__ counts, float* __restrict__ pair_sums) {
    __shared__ int lab[4096];  // B <= 4096 in this harness
    __shared__ unsigned wcnt[4][NDOM];
    int t = threadIdx.x, lane = t & 63, wv = t >> 6;

    int nv = (B + 3) >> 2;
    for (int c = t; c < nv; c += 256) {
        int4 v = ((const int4*)labels)[c];
        ((int4*)lab)[c] = v;
    }
    __syncthreads();

    int nch = (B + 63) >> 6;
    int cpw = (nch + 3) >> 2;
    int c0 = wv * cpw, c1 = min(c0 + cpw, nch);
    unsigned long long below = (1ull << lane) - 1ull;

    unsigned cnt[NDOM];
#pragma unroll
    for (int d = 0; d < NDOM; ++d) cnt[d] = 0;
    for (int c = c0; c < c1; ++c) {
        int i = c * 64 + lane;
        int d = (i < B) ? lab[i] : -1;
#pragma unroll
        for (int dd = 0; dd < NDOM; ++dd)
            cnt[dd] += (unsigned)__popcll(__ballot(d == dd));
    }
    if (lane == 0)
#pragma unroll
        for (int dd = 0; dd < NDOM; ++dd) wcnt[wv][dd] = cnt[dd];
    __syncthreads();

    unsigned tot[NDOM], offs[NDOM + 1];
    offs[0] = 0;
#pragma unroll
    for (int dd = 0; dd < NDOM; ++dd) {
        tot[dd] = wcnt[0][dd] + wcnt[1][dd] + wcnt[2][dd] + wcnt[3][dd];
        offs[dd + 1] = offs[dd] + tot[dd];
    }
    if (t < NDOM) { counts[t] = (int)tot[t]; pair_sums[t] = 0.f; }
    if (t <= NDOM) dom_off[t] = (int)offs[t];

    unsigned run[NDOM];
#pragma unroll
    for (int dd = 0; dd < NDOM; ++dd) {
        unsigned base = offs[dd];
        for (int w = 0; w < 4; ++w)
            if (w < wv) base += wcnt[w][dd];
        run[dd] = base;
    }
    for (int c = c0; c < c1; ++c) {
        int i = c * 64 + lane;
        int d = (i < B) ? lab[i] : -1;
        int pos = -1;
#pragma unroll
        for (int dd = 0; dd < NDOM; ++dd) {
            unsigned long long m = __ballot(d == dd);
            if (d == dd) pos = (int)run[dd] + __popcll(m & below);
            run[dd] += (unsigned)__popcll(m);
        }
        if (i < B) perm[pos] = i;
    }
}

// ---------------------------------------------------------------- gather ----
// One 256-thread block per grouped row: whole 1024-elem row in one float4/lane.
__global__ void k_gather(const float* __restrict__ F, const int* __restrict__ perm,
                         unsigned short* __restrict__ Fb, float* __restrict__ sq,
                         int K) {
    int p = blockIdx.x;
    int i = perm[p];
    int t = threadIdx.x, lane = t & 63, wv = t >> 6;
    const float4* src = (const float4*)(F + (size_t)i * K);
    ushort4* dst = (ushort4*)(Fb + (size_t)p * K);
    float ss = 0.f;
    int nv = K >> 2;
    for (int c = t; c < nv; c += 256) {
        float4 v = src[c];
        ushort4 o;
        o.x = f2bf(v.x); o.y = f2bf(v.y); o.z = f2bf(v.z); o.w = f2bf(v.w);
        dst[c] = o;
        ss += v.x * v.x + v.y * v.y + v.z * v.z + v.w * v.w;
    }
#pragma unroll
    for (int s = 32; s > 0; s >>= 1) ss += __shfl_xor(ss, s);
    __shared__ float wsum[4];
    if (lane == 0) wsum[wv] = ss;
    __syncthreads();
    if (t == 0) sq[p] = wsum[0] + wsum[1] + wsum[2] + wsum[3];
}

// ------------------------------------------------------------------ gram ----
// Upper-triangle 32x32 tiles per domain (off-diagonal weight 2). Persistent
// grid-stride blocks; 4 waves, each wave owns one 16x16 subtile. BK=128,
// global_load_lds staging with global-side XOR chunk swizzle -> conflict-free
// ds_read_b128 (2-way only).
__global__ __launch_bounds__(256) void k_gram(
    const unsigned short* __restrict__ Fb, const float* __restrict__ sq,
    const int* __restrict__ dom_off, float* __restrict__ pair_sums, int K) {
    __shared__ unsigned short lA[TN * BK], lB[TN * BK];  // 8 KB each
    __shared__ int s_offs[NDOM + 1], s_tstart[NDOM + 1], s_nt[NDOM];

    int t = threadIdx.x, lane = t & 63, wv = t >> 6;
    int m16 = lane & 15, quad = lane >> 4;
    int wm = (wv & 1) * 16, wn = (wv >> 1) * 16;

    if (t == 0) {
        int T = 0;
        for (int d = 0; d < NDOM; ++d) {
            s_offs[d] = dom_off[d];
            s_tstart[d] = T;
            int n = dom_off[d + 1] - dom_off[d];
            int nt = (n + TN - 1) / TN;
            s_nt[d] = nt;
            T += nt * (nt + 1) / 2;  // upper triangle incl. diagonal
        }
        s_offs[NDOM] = dom_off[NDOM];
        s_tstart[NDOM] = T;
    }
    __syncthreads();
    int T = s_tstart[NDOM];

    // staging decode (constant across tiles): call h covers rows h*16+wv*4..+4
    // lane -> row r, dest chunk-slot s = lane&15; global chunk c = s ^ (r&15)
    int rr[2], cc[2];
#pragma unroll
    for (int h = 0; h < 2; ++h) {
        rr[h] = h * 16 + wv * 4 + (lane >> 4);
        cc[h] = (lane & 15) ^ (rr[h] & 15);
    }

    for (int tile = blockIdx.x; tile < T; tile += gridDim.x) {
        int dom = 0;
        while (tile >= s_tstart[dom + 1]) ++dom;
        int off = s_offs[dom], n = s_offs[dom + 1] - off;
        int nt = s_nt[dom];
        int rel = tile - s_tstart[dom];
        int ty = 0, rem = rel;
        while (rem >= nt - ty) { rem -= nt - ty; ++ty; }
        int tx = ty + rem;
        int tr = ty * TN, tc = tx * TN;
        float w = (ty == tx) ? 1.f : 2.f;

        const unsigned short* gA[2];
        const unsigned short* gB[2];
#pragma unroll
        for (int h = 0; h < 2; ++h) {
            gA[h] = Fb + (size_t)(off + min(tr + rr[h], n - 1)) * K + cc[h] * 8;
            gB[h] = Fb + (size_t)(off + min(tc + rr[h], n - 1)) * K + cc[h] * 8;
        }

        f32x4 acc = (f32x4){0.f, 0.f, 0.f, 0.f};
        for (int kb = 0; kb < K; kb += BK) {
#pragma unroll
            for (int h = 0; h < 2; ++h) {
                int ldso = (h * 16 + wv * 4) * BK;  // ushort offset, wave-uniform
                gload16(gA[h] + kb, lA + ldso);
                gload16(gB[h] + kb, lB + ldso);
            }
            __syncthreads();
#pragma unroll
            for (int ks = 0; ks < 4; ++ks) {
                int ca = (ks * 4 + quad);
                short8 af = *(const short8*)(lA + ((wm + m16) * 16 + (ca ^ m16)) * 8);
                short8 bg = *(const short8*)(lB + ((wn + m16) * 16 + (ca ^ m16)) * 8);
                acc = __builtin_amdgcn_mfma_f32_16x16x32_bf16(af, bg, acc, 0, 0, 0);
            }
            __syncthreads();
        }

        // epilogue: D[row=quad*4+r][col=m16]; relu(1-dist), weight w
        float local = 0.f;
        int pr0 = tr + wm + quad * 4;
        int pc = tc + wn + m16;
        float sb = (pc < n) ? sq[off + pc] : 0.f;
#pragma unroll
        for (int r = 0; r < 4; ++r) {
            int pr = pr0 + r;
            if (pr < n && pc < n) {
                float val;
                if (pr == pc) {
                    val = 1.0f;  // exact: dist(i,i) == 0
                } else {
                    float d2 = sq[off + pr] + sb - 2.0f * acc[r];
                    d2 = fmaxf(d2, 0.f);
                    val = fmaxf(1.0f - sqrtf(d2), 0.f);
                }
                local += val;
            }
        }
        local *= w;
#pragma unroll
        for (int s = 32; s > 0; s >>= 1) local += __shfl_xor(local, s);
        if (lane == 0) atomicAdd(&pair_sums[dom], local);
    }
}

// -------------------------------------------------------------- finalize ----
__global__ void k_final(const float* __restrict__ pair_sums,
                        const int* __restrict__ counts, float* __restrict__ out) {
    if (threadIdx.x == 0) {
        float s = 0.f;
        int v = 0;
        for (int d = 0; d < NDOM; ++d) {
            int n = counts[d];
            if (n > 1) {
                s += pair_sums[d] / ((float)n * (float)n);
                ++v;
            }
        }
        out[0] = (v > 0) ? s / (float)v : 0.f;
    }
}

// ---------------------------------------------------------------- launch ----
extern "C" void kernel_launch(void* const* d_in, const int* in_sizes, int n_in,
                              void* d_out, int out_size, void* d_ws, size_t ws_size,
                              hipStream_t stream) {
    const float* F = (const float*)d_in[0];
    const int* labels = (const int*)d_in[1];
    int B = in_sizes[1];
    int K = in_sizes[0] / B;  // 4096, 1024

    char* ws = (char*)d_ws;
    size_t o = 0;
    unsigned short* Fb = (unsigned short*)(ws + o);
    o += (size_t)B * K * sizeof(unsigned short);
    o = (o + 255) & ~(size_t)255;
    float* sq = (float*)(ws + o);
    o += (size_t)B * sizeof(float);
    o = (o + 255) & ~(size_t)255;
    int* perm = (int*)(ws + o);
    o += (size_t)B * sizeof(int);
    o = (o + 255) & ~(size_t)255;
    int* dom_off = (int*)(ws + o);
    o += (NDOM + 1) * sizeof(int);
    o = (o + 255) & ~(size_t)255;
    int* counts = (int*)(ws + o);
    o += NDOM * sizeof(int);
    o = (o + 255) & ~(size_t)255;
    float* pair_sums = (float*)(ws + o);

    k_bucket<<<1, 256, 0, stream>>>(labels, B, perm, dom_off, counts, pair_sums);
    k_gather<<<B, 256, 0, stream>>>(F, perm, Fb, sq, K);
    k_gram<<<2048, 256, 0, stream>>>(Fb, sq, dom_off, pair_sums, K);
    k_final<<<1, 64, 0, stream>>>(pair_sums, counts, (float*)d_out);
}